// Round 3
// baseline (55.948 us; speedup 1.0000x reference)
//
#include <hip/hip_runtime.h>

// Problem constants (from reference)
#define BATCH        64
#define T_LEN        512
#define I_LEN        256
#define SEQ          (T_LEN + I_LEN + 2)   // 770
#define EMB_D        768
#define D4           (EMB_D / 4)           // 192 float4 per row
#define IMG_START_ID 30522
#define IMG_END_ID   30523

#define GRID_BLOCKS  2310                  // 591,360 threads; total4 = 16 * stride exactly
#define UNROLL       4
#define OUTER_ITERS  4                     // 16 / UNROLL

typedef float f32x4 __attribute__((ext_vector_type(4)));

// Fused gather + type-add + types/mask kernel.
// Manual 4x unroll: each group issues 4 independent index loads, then 4
// independent row-gather loads (4 HBM loads in flight per thread), then 4
// nontemporal stores. total4 == 16 * stride exactly -> no tail predication.
__global__ void __launch_bounds__(256)
mm_fused_kernel(const int*   __restrict__ text_ids,     // [B, T]
                const int*   __restrict__ image_tokens, // [B, I]
                const f32x4* __restrict__ text_emb,     // [30524, 192]
                const f32x4* __restrict__ image_emb,    // [8192, 192]
                const f32x4* __restrict__ type_emb,     // [2, 192]
                f32x4*       __restrict__ out_emb,      // [B*SEQ*192]
                float*       __restrict__ out_types,    // [B*SEQ]
                float*       __restrict__ out_mask)     // [B*SEQ]
{
    const unsigned stride = gridDim.x * blockDim.x;            // 591,360
    unsigned g0 = blockIdx.x * blockDim.x + threadIdx.x;

    for (unsigned outer = 0; outer < OUTER_ITERS; ++outer) {
        unsigned gs[UNROLL], c4s[UNROLL], rows[UNROLL], trows[UNROLL];
        const f32x4* srcs[UNROLL];

        // Phase 1: addresses + index loads (4 independent chains issued together)
        #pragma unroll
        for (int k = 0; k < UNROLL; ++k) {
            unsigned g   = g0 + (unsigned)k * stride;
            unsigned row = g / D4;
            unsigned c4  = g - row * D4;
            unsigned b   = row / SEQ;
            unsigned pos = row - b * SEQ;

            const f32x4* src;
            unsigned trow;
            if (pos < T_LEN) {
                int tok = text_ids[b * T_LEN + pos];
                src = text_emb + (unsigned)tok * D4;
                trow = 0;
            } else if (pos == T_LEN) {
                src = text_emb + (unsigned)IMG_START_ID * D4;
                trow = 0;
            } else if (pos < T_LEN + 1 + I_LEN) {
                int tok = image_tokens[b * I_LEN + (pos - T_LEN - 1)];
                src = image_emb + (unsigned)tok * D4;
                trow = 1;
            } else {
                src = text_emb + (unsigned)IMG_END_ID * D4;
                trow = 0;
            }
            gs[k] = g; c4s[k] = c4; rows[k] = row; trows[k] = trow; srcs[k] = src;
        }

        // Phase 2: gather loads — 4 independent HBM reads in flight
        f32x4 vs[UNROLL];
        #pragma unroll
        for (int k = 0; k < UNROLL; ++k)
            vs[k] = srcs[k][c4s[k]];

        // Phase 3: type add + stores
        #pragma unroll
        for (int k = 0; k < UNROLL; ++k) {
            f32x4 v = vs[k] + type_emb[trows[k] * D4 + c4s[k]];
            __builtin_nontemporal_store(v, &out_emb[gs[k]]);
            if (c4s[k] == 0) {
                __builtin_nontemporal_store(trows[k] ? 1.0f : 0.0f, &out_types[rows[k]]);
                __builtin_nontemporal_store(1.0f, &out_mask[rows[k]]);
            }
        }

        g0 += UNROLL * stride;
    }
}

extern "C" void kernel_launch(void* const* d_in, const int* in_sizes, int n_in,
                              void* d_out, int out_size, void* d_ws, size_t ws_size,
                              hipStream_t stream) {
    const int*   text_ids     = (const int*)d_in[0];
    const int*   image_tokens = (const int*)d_in[1];
    const f32x4* text_emb     = (const f32x4*)d_in[2];
    const f32x4* image_emb    = (const f32x4*)d_in[3];
    const f32x4* type_emb     = (const f32x4*)d_in[4];

    float* out = (float*)d_out;
    const unsigned emb_elems = (unsigned)BATCH * SEQ * EMB_D;   // 37,847,040
    const unsigned row_elems = (unsigned)BATCH * SEQ;           // 49,280
    float* out_types = out + emb_elems;
    float* out_mask  = out_types + row_elems;

    mm_fused_kernel<<<dim3(GRID_BLOCKS), dim3(256), 0, stream>>>(
        text_ids, image_tokens, text_emb, image_emb, type_emb,
        (f32x4*)out, out_types, out_mask);
}

// Round 4
// 49.024 us; speedup vs baseline: 1.1412x; 1.1412x over previous
//
#include <hip/hip_runtime.h>

// Problem constants (from reference)
#define BATCH        64
#define T_LEN        512
#define I_LEN        256
#define SEQ          (T_LEN + I_LEN + 2)   // 770
#define EMB_D        768
#define D4           (EMB_D / 4)           // 192 float4 per row
#define IMG_START_ID 30522
#define IMG_END_ID   30523

#define ROWS_PER_BLOCK 2
#define BLOCK          (ROWS_PER_BLOCK * 192)   // 384 threads = 6 waves
#define N_ROWS         (BATCH * SEQ)            // 49,280
#define GRID           (N_ROWS / ROWS_PER_BLOCK) // 24,640 (N_ROWS even)

typedef float f32x4 __attribute__((ext_vector_type(4)));

// Row-aligned mapping: each row (770 positions x 768 floats) is 192 float4 =
// exactly 3 waves x 64 lanes x 16B. No wave straddles a row -> every branch
// and every token-index load is wave-uniform (compiler scalarizes to s_load).
// One 16B load + one 16B nontemporal store per thread, no loop, no division
// beyond one magic-mul per thread.
__global__ void __launch_bounds__(BLOCK)
mm_row_kernel(const int*   __restrict__ text_ids,     // [B, T]
              const int*   __restrict__ image_tokens, // [B, I]
              const f32x4* __restrict__ text_emb,     // [30524, 192]
              const f32x4* __restrict__ image_emb,    // [8192, 192]
              const f32x4* __restrict__ type_emb,     // [2, 192]
              f32x4*       __restrict__ out_emb,      // [B*SEQ*192]
              float*       __restrict__ out_types,    // [B*SEQ]
              float*       __restrict__ out_mask)     // [B*SEQ]
{
    unsigned t   = threadIdx.x;
    unsigned r   = (t >= 192) ? 1u : 0u;         // row slot within block
    unsigned c4  = t - r * 192;                  // [0, 192)
    unsigned row = blockIdx.x * ROWS_PER_BLOCK + r;
    unsigned b   = row / SEQ;                    // magic-mul
    unsigned pos = row - b * SEQ;

    const f32x4* src;
    unsigned trow;
    if (pos < T_LEN) {
        int tok = text_ids[b * T_LEN + pos];     // wave-uniform address
        src = text_emb + (unsigned)tok * D4;
        trow = 0;
    } else if (pos == T_LEN) {
        src = text_emb + (unsigned)IMG_START_ID * D4;
        trow = 0;
    } else if (pos < T_LEN + 1 + I_LEN) {
        int tok = image_tokens[b * I_LEN + (pos - T_LEN - 1)];
        src = image_emb + (unsigned)tok * D4;
        trow = 1;
    } else {
        src = text_emb + (unsigned)IMG_END_ID * D4;
        trow = 0;
    }

    f32x4 v = src[c4] + type_emb[trow * D4 + c4];
    __builtin_nontemporal_store(v, &out_emb[(unsigned)row * D4 + c4]);

    if (c4 == 0) {
        __builtin_nontemporal_store(trow ? 1.0f : 0.0f, &out_types[row]);
        __builtin_nontemporal_store(1.0f, &out_mask[row]);
    }
}

extern "C" void kernel_launch(void* const* d_in, const int* in_sizes, int n_in,
                              void* d_out, int out_size, void* d_ws, size_t ws_size,
                              hipStream_t stream) {
    const int*   text_ids     = (const int*)d_in[0];
    const int*   image_tokens = (const int*)d_in[1];
    const f32x4* text_emb     = (const f32x4*)d_in[2];
    const f32x4* image_emb    = (const f32x4*)d_in[3];
    const f32x4* type_emb     = (const f32x4*)d_in[4];

    float* out = (float*)d_out;
    const unsigned emb_elems = (unsigned)BATCH * SEQ * EMB_D;   // 37,847,040
    const unsigned row_elems = (unsigned)BATCH * SEQ;           // 49,280
    float* out_types = out + emb_elems;
    float* out_mask  = out_types + row_elems;

    mm_row_kernel<<<dim3(GRID), dim3(BLOCK), 0, stream>>>(
        text_ids, image_tokens, text_emb, image_emb, type_emb,
        (f32x4*)out, out_types, out_mask);
}